// Round 1
// baseline (276.520 us; speedup 1.0000x reference)
//
#include <hip/hip_runtime.h>
#include <hip/hip_bf16.h>

// Loss = L1*sl1(1,iou) + L2*sl1(t[:4],p[:4]) + L3*sl1(t[12],p[12]) + 0.5*L4*sl1(t[4:12],p[4:12])
// shapes: (B=256, N=8192, F=13) fp32. B*N = 2^21 rows.

#define ROWS_TOTAL   (256 * 8192)        // 2097152 = 2^21
#define ROWS_PER_BLK 256
#define FLOATS_PER_CHUNK (ROWS_PER_BLK * 13)   // 3328 floats = 832 float4 (13312 B, 16-aligned per chunk)
#define F4_PER_CHUNK (FLOATS_PER_CHUNK / 4)    // 832

__device__ __forceinline__ float sl1(float d) {
    d = fabsf(d);
    return d < 1.0f ? 0.5f * d * d : d - 0.5f;
}

__global__ __launch_bounds__(256) void loss_kernel(const float* __restrict__ targets,
                                                   const float* __restrict__ preds,
                                                   float* __restrict__ out) {
    __shared__ float st[FLOATS_PER_CHUNK];
    __shared__ float sp[FLOATS_PER_CHUNK];
    __shared__ float wave_part[4];

    const int tid   = threadIdx.x;
    const int chunk = blockIdx.x;                    // 8192 chunks, one per block
    const long long base = (long long)chunk * FLOATS_PER_CHUNK;

    // Stage chunk into LDS with fully-coalesced float4 loads.
    const float4* gt = (const float4*)(targets + base);
    const float4* gp = (const float4*)(preds + base);
    float4* lt = (float4*)st;
    float4* lp = (float4*)sp;
#pragma unroll
    for (int k = 0; k < 4; ++k) {
        int i = k * 256 + tid;
        if (i < F4_PER_CHUNK) {
            lt[i] = gt[i];
            lp[i] = gp[i];
        }
    }
    __syncthreads();

    // Each thread computes one row of 13 features from LDS.
    const int rb = tid * 13;
    float t0 = st[rb+0],  t1 = st[rb+1],  t2 = st[rb+2],  t3 = st[rb+3];
    float p0 = sp[rb+0],  p1 = sp[rb+1],  p2 = sp[rb+2],  p3 = sp[rb+3];

    // loss2: first 4 features
    float s2 = sl1(t0-p0) + sl1(t1-p1) + sl1(t2-p2) + sl1(t3-p3);

    // loss4: features 4..11
    float s4 = 0.0f;
#pragma unroll
    for (int f = 4; f < 12; ++f) s4 += sl1(st[rb+f] - sp[rb+f]);

    // loss3: feature 12
    float s3 = sl1(st[rb+12] - sp[rb+12]);

    // loss1: IoU term
    float xx1 = fmaxf(t0, p0);
    float yy1 = fmaxf(t1, p1);
    float xx2 = fminf(t2, p2);
    float yy2 = fminf(t3, p3);
    float w = fmaxf(xx2 - xx1, 0.0f);
    float h = fmaxf(yy2 - yy1, 0.0f);
    float inter = w * h;
    float area1 = (t2 - t0) * (t3 - t1);
    float area2 = (p2 - p0) * (p3 - p1);
    float iou = inter / (area1 + area2 - inter + 1e-7f);
    float s1 = sl1(1.0f - iou);

    // Exact power-of-two mean weights: B*N = 2^21.
    constexpr float W1 = 1.0f / 2097152.0f;    // 1/(B*N)
    constexpr float W2 = 1.0f / 8388608.0f;    // 1/(B*N*4)
    constexpr float W3 = 1.0f / 2097152.0f;    // 1/(B*N)
    constexpr float W4 = 1.0f / 33554432.0f;   // 0.5 / (B*N*8)

    float c = W1 * s1 + W2 * s2 + W3 * s3 + W4 * s4;

    // Wave64 reduction
#pragma unroll
    for (int off = 32; off > 0; off >>= 1)
        c += __shfl_down(c, off, 64);

    const int wave = tid >> 6;
    const int lane = tid & 63;
    if (lane == 0) wave_part[wave] = c;
    __syncthreads();
    if (tid == 0) {
        float blk = wave_part[0] + wave_part[1] + wave_part[2] + wave_part[3];
        atomicAdd(out, blk);
    }
}

extern "C" void kernel_launch(void* const* d_in, const int* in_sizes, int n_in,
                              void* d_out, int out_size, void* d_ws, size_t ws_size,
                              hipStream_t stream) {
    const float* targets = (const float*)d_in[0];
    const float* preds   = (const float*)d_in[1];
    float* out = (float*)d_out;

    // d_out is re-poisoned (0xAA) before every timed launch — zero it on stream.
    hipMemsetAsync(out, 0, sizeof(float), stream);

    const int blocks = ROWS_TOTAL / ROWS_PER_BLK;   // 8192
    loss_kernel<<<blocks, 256, 0, stream>>>(targets, preds, out);
}

// Round 2
// 268.971 us; speedup vs baseline: 1.0281x; 1.0281x over previous
//
#include <hip/hip_runtime.h>
#include <hip/hip_bf16.h>

// Loss = L1*sl1(1,iou) + L2*sl1(t[:4],p[:4]) + L3*sl1(t[12],p[12]) + 0.5*L4*sl1(t[4:12],p[4:12])
// shapes: (B=256, N=8192, F=13) fp32. B*N = 2^21 rows.
//
// Structure: stage1 = 1536 persistent blocks (6/CU, LDS-capacity-resident),
// grid-stride over 8192 chunks of 256 rows, software-pipelined global->reg->LDS
// staging; per-block partial to d_ws. stage2 = single block sums 1536 partials.
// No same-address atomics, no memset dispatch.

#define NCHUNK          8192
#define ROWS_PER_CHUNK  256
#define FPC             (ROWS_PER_CHUNK * 13)   // 3328 floats per tensor-chunk
#define F4PC            (FPC / 4)               // 832 float4 (chunk base 13312 B, 16-aligned)
#define NBLK            1536                    // 6 blocks/CU * 256 CUs

__device__ __forceinline__ float sl1(float d) {
    d = fabsf(d);
    return d < 1.0f ? 0.5f * d * d : d - 0.5f;
}

__global__ __launch_bounds__(256) void loss_stage1(const float* __restrict__ T,
                                                   const float* __restrict__ P,
                                                   float* __restrict__ partial) {
    __shared__ float st[FPC];
    __shared__ float sp[FPC];
    __shared__ float wred[4];

    const int tid = threadIdx.x;
    float4 at[4], ap[4];

    int c = blockIdx.x;

    // Prime the pipeline: issue chunk c's global loads into registers.
    {
        const float4* gt = (const float4*)(T + (long long)c * FPC);
        const float4* gp = (const float4*)(P + (long long)c * FPC);
#pragma unroll
        for (int k = 0; k < 4; ++k) {
            int i = k * 256 + tid;
            if (i < F4PC) { at[k] = gt[i]; ap[k] = gp[i]; }
        }
    }

    float acc = 0.0f;
    while (c < NCHUNK) {
        const int cn = c + NBLK;

        // Drain staged registers into LDS (compiler inserts the vmcnt wait).
        float4* lt = (float4*)st;
        float4* lp = (float4*)sp;
#pragma unroll
        for (int k = 0; k < 4; ++k) {
            int i = k * 256 + tid;
            if (i < F4PC) { lt[i] = at[k]; lp[i] = ap[k]; }
        }
        __syncthreads();

        // Prefetch next chunk's global loads — overlaps the compute below.
        if (cn < NCHUNK) {
            const float4* gt = (const float4*)(T + (long long)cn * FPC);
            const float4* gp = (const float4*)(P + (long long)cn * FPC);
#pragma unroll
            for (int k = 0; k < 4; ++k) {
                int i = k * 256 + tid;
                if (i < F4PC) { at[k] = gt[i]; ap[k] = gp[i]; }
            }
        }

        // Compute one row (13 features) per thread from LDS.
        const int rb = tid * 13;
        float t0 = st[rb+0], t1 = st[rb+1], t2 = st[rb+2], t3 = st[rb+3];
        float p0 = sp[rb+0], p1 = sp[rb+1], p2 = sp[rb+2], p3 = sp[rb+3];

        float s2 = sl1(t0-p0) + sl1(t1-p1) + sl1(t2-p2) + sl1(t3-p3);

        float s4 = 0.0f;
#pragma unroll
        for (int f = 4; f < 12; ++f) s4 += sl1(st[rb+f] - sp[rb+f]);

        float s3 = sl1(st[rb+12] - sp[rb+12]);

        float xx1 = fmaxf(t0, p0);
        float yy1 = fmaxf(t1, p1);
        float xx2 = fminf(t2, p2);
        float yy2 = fminf(t3, p3);
        float w = fmaxf(xx2 - xx1, 0.0f);
        float h = fmaxf(yy2 - yy1, 0.0f);
        float inter = w * h;
        float a1 = (t2 - t0) * (t3 - t1);
        float a2 = (p2 - p0) * (p3 - p1);
        float iou = inter / (a1 + a2 - inter + 1e-7f);
        float s1 = sl1(1.0f - iou);

        // Exact power-of-two mean weights: B*N = 2^21.
        constexpr float W1 = 1.0f / 2097152.0f;    // 1/(B*N)
        constexpr float W2 = 1.0f / 8388608.0f;    // 1/(B*N*4)
        constexpr float W3 = 1.0f / 2097152.0f;    // 1/(B*N)
        constexpr float W4 = 1.0f / 33554432.0f;   // 0.5/(B*N*8)
        acc += W1*s1 + W2*s2 + W3*s3 + W4*s4;

        __syncthreads();   // LDS reused next iteration
        c = cn;
    }

    // Block reduction: wave64 shuffle -> 4-wave LDS -> one partial per block.
#pragma unroll
    for (int off = 32; off > 0; off >>= 1)
        acc += __shfl_down(acc, off, 64);
    if ((tid & 63) == 0) wred[tid >> 6] = acc;
    __syncthreads();
    if (tid == 0)
        partial[blockIdx.x] = wred[0] + wred[1] + wred[2] + wred[3];
}

__global__ __launch_bounds__(256) void loss_stage2(const float* __restrict__ partial,
                                                   float* __restrict__ out) {
    __shared__ float wred[4];
    const int tid = threadIdx.x;
    float a = 0.0f;
    for (int i = tid; i < NBLK; i += 256) a += partial[i];
#pragma unroll
    for (int off = 32; off > 0; off >>= 1)
        a += __shfl_down(a, off, 64);
    if ((tid & 63) == 0) wred[tid >> 6] = a;
    __syncthreads();
    if (tid == 0) out[0] = wred[0] + wred[1] + wred[2] + wred[3];
}

extern "C" void kernel_launch(void* const* d_in, const int* in_sizes, int n_in,
                              void* d_out, int out_size, void* d_ws, size_t ws_size,
                              hipStream_t stream) {
    const float* targets = (const float*)d_in[0];
    const float* preds   = (const float*)d_in[1];
    float* out     = (float*)d_out;
    float* partial = (float*)d_ws;   // NBLK floats of scratch

    loss_stage1<<<NBLK, 256, 0, stream>>>(targets, preds, partial);
    loss_stage2<<<1, 256, 0, stream>>>(partial, out);
}

// Round 3
// 226.779 us; speedup vs baseline: 1.2193x; 1.1861x over previous
//
#include <hip/hip_runtime.h>
#include <hip/hip_bf16.h>

// Loss = L1*sl1(1,iou) + L2*sl1(t[:4],p[:4]) + L3*sl1(t[12],p[12]) + 0.5*L4*sl1(t[4:12],p[4:12])
// shapes: (B=256, N=8192, F=13) fp32. B*N = 2^21 rows.
//
// stage1: 768 persistent blocks (3/CU; LDS 53 KB double-buffered), grid-stride
// over 8192 chunks of 256 rows. Staging via __builtin_amdgcn_global_load_lds
// (16 B/lane, async direct-to-LDS — no VGPR round trip, nothing to spill).
// One barrier per iteration: drain cur buffer, issue next buffer, compute cur.
// stage2: one block sums 768 partials. No same-address atomics, no memset.

#define NCHUNK 8192
#define RPC    256
#define FPC    (RPC * 13)        // 3328 floats = 13312 B per tensor-chunk
#define SEGS   13                // 13 segments of 1 KB (64 lanes x 16 B)
#define NBLK   768               // 3 blocks/CU * 256 CU

typedef const __attribute__((address_space(1))) float gfloat;
typedef __attribute__((address_space(3))) float lfloat;

__device__ __forceinline__ float sl1(float d) {
    d = fabsf(d);
    return d < 1.0f ? 0.5f * d * d : d - 0.5f;
}

__global__ __launch_bounds__(256) void loss_stage1(const float* __restrict__ T,
                                                   const float* __restrict__ P,
                                                   float* __restrict__ partial) {
    __shared__ float st[2][FPC];
    __shared__ float sp[2][FPC];
    __shared__ float wred[4];

    const int tid  = threadIdx.x;
    const int lane = tid & 63;
    const int wv   = tid >> 6;

    // Async-stage chunk c into LDS buffer b. Wave wv handles segments
    // wv, wv+4, wv+8, (wv==0: 12) for both tensors. Lane i's 16 B lands at
    // segment base + i*16 — contiguous layout matches the HW scatter rule.
    auto stage = [&](int c, int b) {
        const long long gb = (long long)c * FPC + lane * 4;
        for (int s = wv; s < SEGS; s += 4) {
            __builtin_amdgcn_global_load_lds((gfloat*)(T + gb + s * 256),
                                             (lfloat*)&st[b][s * 256 + lane * 4],
                                             16, 0, 0);
            __builtin_amdgcn_global_load_lds((gfloat*)(P + gb + s * 256),
                                             (lfloat*)&sp[b][s * 256 + lane * 4],
                                             16, 0, 0);
        }
    };

    int c   = blockIdx.x;
    int cur = 0;
    float acc = 0.0f;

    stage(c, 0);   // prime the pipe

    for (; c < NCHUNK; c += NBLK) {
        __syncthreads();   // drains vmcnt: buf[cur] ready; prior compute on buf[cur^1] done

        const int cn = c + NBLK;
        if (cn < NCHUNK) stage(cn, cur ^ 1);   // async prefetch overlaps compute below

        // Compute one row (13 features) per thread from buf[cur].
        const float* t = st[cur];
        const float* p = sp[cur];
        const int rb = tid * 13;

        float t0 = t[rb+0], t1 = t[rb+1], t2 = t[rb+2], t3 = t[rb+3];
        float p0 = p[rb+0], p1 = p[rb+1], p2 = p[rb+2], p3 = p[rb+3];

        float s2 = sl1(t0-p0) + sl1(t1-p1) + sl1(t2-p2) + sl1(t3-p3);

        float s4 = 0.0f;
#pragma unroll
        for (int f = 4; f < 12; ++f) s4 += sl1(t[rb+f] - p[rb+f]);

        float s3 = sl1(t[rb+12] - p[rb+12]);

        float xx1 = fmaxf(t0, p0);
        float yy1 = fmaxf(t1, p1);
        float xx2 = fminf(t2, p2);
        float yy2 = fminf(t3, p3);
        float w  = fmaxf(xx2 - xx1, 0.0f);
        float h  = fmaxf(yy2 - yy1, 0.0f);
        float inter = w * h;
        float a1 = (t2 - t0) * (t3 - t1);
        float a2 = (p2 - p0) * (p3 - p1);
        float iou = inter / (a1 + a2 - inter + 1e-7f);
        float s1 = sl1(1.0f - iou);

        // Exact power-of-two mean weights: B*N = 2^21.
        constexpr float W1 = 1.0f / 2097152.0f;    // 1/(B*N)
        constexpr float W2 = 1.0f / 8388608.0f;    // 1/(B*N*4)
        constexpr float W3 = 1.0f / 2097152.0f;    // 1/(B*N)
        constexpr float W4 = 1.0f / 33554432.0f;   // 0.5/(B*N*8)
        acc += W1*s1 + W2*s2 + W3*s3 + W4*s4;

        cur ^= 1;
    }

    // Block reduction: wave64 shuffle -> 4-wave LDS -> one partial per block.
#pragma unroll
    for (int off = 32; off > 0; off >>= 1)
        acc += __shfl_down(acc, off, 64);
    if (lane == 0) wred[wv] = acc;
    __syncthreads();
    if (tid == 0)
        partial[blockIdx.x] = wred[0] + wred[1] + wred[2] + wred[3];
}

__global__ __launch_bounds__(256) void loss_stage2(const float* __restrict__ partial,
                                                   float* __restrict__ out) {
    __shared__ float wred[4];
    const int tid = threadIdx.x;
    float a = 0.0f;
    for (int i = tid; i < NBLK; i += 256) a += partial[i];
#pragma unroll
    for (int off = 32; off > 0; off >>= 1)
        a += __shfl_down(a, off, 64);
    if ((tid & 63) == 0) wred[tid >> 6] = a;
    __syncthreads();
    if (tid == 0) out[0] = wred[0] + wred[1] + wred[2] + wred[3];
}

extern "C" void kernel_launch(void* const* d_in, const int* in_sizes, int n_in,
                              void* d_out, int out_size, void* d_ws, size_t ws_size,
                              hipStream_t stream) {
    const float* targets = (const float*)d_in[0];
    const float* preds   = (const float*)d_in[1];
    float* out     = (float*)d_out;
    float* partial = (float*)d_ws;   // NBLK floats of scratch

    loss_stage1<<<NBLK, 256, 0, stream>>>(targets, preds, partial);
    loss_stage2<<<1, 256, 0, stream>>>(partial, out);
}